// Round 17
// baseline (30406.055 us; speedup 1.0000x reference)
//
#include <hip/hip_runtime.h>
#include <math.h>

// Problem constants
#define BATCH   8192
#define EXP_DIM 1024
#define DICT    4096
#define NIT     20
#define KSP     409
#define STEP_F  0.1f
#define THR_F   0.01f

// Per-output summation is k strictly ascending, single fp32 accumulator
// (bit-identical trajectory to all verified passing rounds).
// HARD INVARIANT: the data has a near-tied top-k boundary at magnitude ~0.46
// (threshold 0.037) — rounds 3-6 proved ANY summation reassociation
// (split-K, Gram restructuring, MFMA multi-term splits) flips it and fails.
#define TK 16
#define LDS_LD 132

__device__ __forceinline__ float soft_update(float oldv, float g) {
    float a = oldv + STEP_F * g;
    float m = fabsf(a) - THR_F;
    return m > 0.0f ? copysignf(m, a) : 0.0f;
}

// ---------------------------------------------------------------------------
// GEMM1: R = X - A*D.  A:[BATCH,DICT]  D:[DICT,EXP_DIM]  X,R:[BATCH,EXP_DIM]
// Round-8's kernel verbatim — best measured gemm1 (963-965 us, VALU 71%,
// Occ 32%): 128(M)x64(N) tile, TK=32, 8x4/thread, 1024 blocks = 4/CU
// (two independent barrier domains per CU hide staging latency).
#define G1_TK 32
#define G1_LDA 132   // AsT leading dim (floats): 128 + 4
#define G1_LDB 68    // Bs  leading dim (floats): 64 + 4

__global__ __launch_bounds__(256)
void gemm1_resid(const float* __restrict__ A, const float* __restrict__ D,
                 const float* __restrict__ X, float* __restrict__ R) {
    __shared__ float AsT[G1_TK][G1_LDA];   // transposed A tile: [k][row]
    __shared__ float Bs [G1_TK][G1_LDB];   // D tile straight:  [k][col]
    const int t  = threadIdx.x;
    const int tx = t & 15;        // 0..15 -> 4 output cols each (64 total)
    const int ty = t >> 4;        // 0..15 -> 8 output rows each (128 total)
    const int row0 = blockIdx.y * 128, col0 = blockIdx.x * 64;

    // A staging: thread t owns (row = t>>1, k-half = (t&1)*16)  [16 floats]
    const int arow = t >> 1, akh = (t & 1) << 4;
    const float* pA = A + (size_t)(row0 + arow) * DICT + akh;
    // B staging: thread t owns (k-row = t>>3, col-group = (t&7)*8) [8 floats]
    const int bkr = t >> 3, bcg = (t & 7) << 3;
    const float* pB = D + (size_t)bkr * EXP_DIM + col0 + bcg;

    float acc[8][4] = {};

    for (int k0 = 0; k0 < DICT; k0 += G1_TK) {
        float4 a0 = *(const float4*)(pA + k0);
        float4 a1 = *(const float4*)(pA + k0 + 4);
        float4 a2 = *(const float4*)(pA + k0 + 8);
        float4 a3 = *(const float4*)(pA + k0 + 12);
        float4 b0 = *(const float4*)(pB + (size_t)k0 * EXP_DIM);
        float4 b1 = *(const float4*)(pB + (size_t)k0 * EXP_DIM + 4);
        __syncthreads();
        AsT[akh +  0][arow] = a0.x; AsT[akh +  1][arow] = a0.y;
        AsT[akh +  2][arow] = a0.z; AsT[akh +  3][arow] = a0.w;
        AsT[akh +  4][arow] = a1.x; AsT[akh +  5][arow] = a1.y;
        AsT[akh +  6][arow] = a1.z; AsT[akh +  7][arow] = a1.w;
        AsT[akh +  8][arow] = a2.x; AsT[akh +  9][arow] = a2.y;
        AsT[akh + 10][arow] = a2.z; AsT[akh + 11][arow] = a2.w;
        AsT[akh + 12][arow] = a3.x; AsT[akh + 13][arow] = a3.y;
        AsT[akh + 14][arow] = a3.z; AsT[akh + 15][arow] = a3.w;
        *(float4*)&Bs[bkr][bcg]     = b0;
        *(float4*)&Bs[bkr][bcg + 4] = b1;
        __syncthreads();
#pragma unroll
        for (int k = 0; k < G1_TK; ++k) {
            float4 av0 = *(const float4*)&AsT[k][ty * 4];
            float4 av1 = *(const float4*)&AsT[k][64 + ty * 4];
            float4 bv  = *(const float4*)&Bs[k][tx * 4];
            float av[8] = {av0.x, av0.y, av0.z, av0.w, av1.x, av1.y, av1.z, av1.w};
            float bvr[4] = {bv.x, bv.y, bv.z, bv.w};
#pragma unroll
            for (int i = 0; i < 8; ++i)
#pragma unroll
                for (int j = 0; j < 4; ++j)
                    acc[i][j] += av[i] * bvr[j];
        }
    }

#pragma unroll
    for (int i = 0; i < 8; ++i) {
        const int r = row0 + ((i < 4) ? (ty * 4 + i) : (64 + ty * 4 + i - 4));
        const size_t off = (size_t)r * EXP_DIM + col0 + tx * 4;
        float4 xv = *(const float4*)&X[off];
        float4 o;
        o.x = xv.x - acc[i][0]; o.y = xv.y - acc[i][1];
        o.z = xv.z - acc[i][2]; o.w = xv.w - acc[i][3];
        *(float4*)&R[off] = o;
    }
}

// ---------------------------------------------------------------------------
// GEMM2: A = soft(A + STEP * R*D^T).  R:[BATCH,EXP_DIM]  D:[DICT,EXP_DIM]
// (byte-identical to rounds 7/8/9/12/14/15/16 — measured ~83% of fp32 peak)
__global__ __launch_bounds__(256)
void gemm2_update(const float* __restrict__ Rsrc, const float* __restrict__ D,
                  float* __restrict__ Aa) {
    __shared__ float AsT[TK][LDS_LD];   // transposed R tile: [k][row]
    __shared__ float BsT[TK][LDS_LD];   // transposed D tile: [k][n]
    const int t  = threadIdx.x;
    const int tx = t & 15, ty = t >> 4;
    const int row0 = blockIdx.y * 128, col0 = blockIdx.x * 128;

    const int arow = t >> 1, akg = (t & 1) << 3;
    const float* pA = Rsrc + (size_t)(row0 + arow) * EXP_DIM + akg;
    const float* pB = D + (size_t)(col0 + arow) * EXP_DIM + akg;

    float acc[8][8] = {};

    for (int k0 = 0; k0 < EXP_DIM; k0 += TK) {
        float4 a0 = *(const float4*)(pA + k0);
        float4 a1 = *(const float4*)(pA + k0 + 4);
        float4 b0 = *(const float4*)(pB + k0);
        float4 b1 = *(const float4*)(pB + k0 + 4);
        __syncthreads();
        AsT[akg + 0][arow] = a0.x; AsT[akg + 1][arow] = a0.y;
        AsT[akg + 2][arow] = a0.z; AsT[akg + 3][arow] = a0.w;
        AsT[akg + 4][arow] = a1.x; AsT[akg + 5][arow] = a1.y;
        AsT[akg + 6][arow] = a1.z; AsT[akg + 7][arow] = a1.w;
        BsT[akg + 0][arow] = b0.x; BsT[akg + 1][arow] = b0.y;
        BsT[akg + 2][arow] = b0.z; BsT[akg + 3][arow] = b0.w;
        BsT[akg + 4][arow] = b1.x; BsT[akg + 5][arow] = b1.y;
        BsT[akg + 6][arow] = b1.z; BsT[akg + 7][arow] = b1.w;
        __syncthreads();
#pragma unroll
        for (int k = 0; k < TK; ++k) {
            float4 av0 = *(const float4*)&AsT[k][ty * 4];
            float4 av1 = *(const float4*)&AsT[k][64 + ty * 4];
            float4 bv0 = *(const float4*)&BsT[k][tx * 4];
            float4 bv1 = *(const float4*)&BsT[k][64 + tx * 4];
            float av[8] = {av0.x, av0.y, av0.z, av0.w, av1.x, av1.y, av1.z, av1.w};
            float bv[8] = {bv0.x, bv0.y, bv0.z, bv0.w, bv1.x, bv1.y, bv1.z, bv1.w};
#pragma unroll
            for (int i = 0; i < 8; ++i)
#pragma unroll
                for (int j = 0; j < 8; ++j)
                    acc[i][j] += av[i] * bv[j];
        }
    }

#pragma unroll
    for (int i = 0; i < 8; ++i) {
        const int r = row0 + ((i < 4) ? (ty * 4 + i) : (64 + ty * 4 + i - 4));
        {
            float4* p = (float4*)&Aa[(size_t)r * DICT + col0 + tx * 4];
            float4 oldv = *p;
            float4 o;
            o.x = soft_update(oldv.x, acc[i][0]);
            o.y = soft_update(oldv.y, acc[i][1]);
            o.z = soft_update(oldv.z, acc[i][2]);
            o.w = soft_update(oldv.w, acc[i][3]);
            *p = o;
        }
        {
            float4* p = (float4*)&Aa[(size_t)r * DICT + col0 + 64 + tx * 4];
            float4 oldv = *p;
            float4 o;
            o.x = soft_update(oldv.x, acc[i][4]);
            o.y = soft_update(oldv.y, acc[i][5]);
            o.z = soft_update(oldv.z, acc[i][6]);
            o.w = soft_update(oldv.w, acc[i][7]);
            *p = o;
        }
    }
}

// ---------------------------------------------------------------------------
// In-place top-KSP by |value| per row (exact MSB-first radix select; verified).
__global__ __launch_bounds__(256)
void topk_kernel(float* __restrict__ A) {
    const int row = blockIdx.x;
    float* a = A + (size_t)row * DICT;
    __shared__ unsigned int sb[DICT];
    __shared__ unsigned int hist[256];
    __shared__ unsigned int s_bin, s_need;
    const int t = threadIdx.x;

#pragma unroll
    for (int i = 0; i < DICT / 256; ++i) {
        int j = t + 256 * i;
        sb[j] = __float_as_uint(a[j]) & 0x7fffffffu;
    }

    unsigned int prefix = 0, needed = KSP;
    for (int shift = 24; shift >= 0; shift -= 8) {
        __syncthreads();
        hist[t] = 0;
        __syncthreads();
        unsigned int hmask = (shift == 24) ? 0u : (0xffffffffu << (shift + 8));
        for (int i = 0; i < DICT / 256; ++i) {
            unsigned int b = sb[t + 256 * i];
            if ((b & hmask) == prefix)
                atomicAdd(&hist[(b >> shift) & 0xffu], 1u);
        }
        __syncthreads();
        if (t == 0) {
            unsigned int cum = 0;
            for (int bin = 255; bin >= 0; --bin) {
                unsigned int h = hist[bin];
                if (cum + h >= needed) { s_bin = (unsigned int)bin; s_need = needed - cum; break; }
                cum += h;
            }
        }
        __syncthreads();
        prefix |= s_bin << shift;
        needed = s_need;
    }

    unsigned int E = hist[prefix & 0xffu];
    bool simple = (E == needed) || (prefix == 0);
    if (!simple) {
        if (t == 0) {
            unsigned int cnt = 0;
            for (int j = 0; j < DICT; ++j) {
                if (sb[j] == prefix) {
                    if (cnt < needed) sb[j] |= 0x80000000u;
                    ++cnt;
                }
            }
        }
        __syncthreads();
    }

    for (int i = 0; i < DICT / 256; ++i) {
        int j = t + 256 * i;
        unsigned int b = sb[j];
        bool keep = simple ? (b >= prefix)
                           : (((b & 0x7fffffffu) > prefix) || (b >> 31));
        float v = a[j];
        a[j] = keep ? v : 0.0f;
    }
}

// ---------------------------------------------------------------------------
extern "C" void kernel_launch(void* const* d_in, const int* in_sizes, int n_in,
                              void* d_out, int out_size, void* d_ws, size_t ws_size,
                              hipStream_t stream) {
    const float* X = (const float*)d_in[0];   // [8192,1024]
    const float* D = (const float*)d_in[1];   // [4096,1024]
    float* A = (float*)d_out;                 // [8192,4096] alpha, iterated in place
    float* R = (float*)d_ws;                  // [8192,1024] residual scratch (33.5 MB)

    hipMemsetAsync(A, 0, (size_t)BATCH * DICT * sizeof(float), stream);

    dim3 blk(256);
    dim3 g1(EXP_DIM / 64, BATCH / 128);   // 16 x 64 = 1024 blocks (4/CU)
    dim3 g2(DICT / 128,   BATCH / 128);   // 32 x 64 = 2048 blocks

    // Iteration 0: A == 0 (memset), so gemm1 would compute R = X - 0 = X
    // bitwise. Skip it and feed X directly to gemm2 — trajectory-identical,
    // saves one full gemm1 dispatch (~990 us).
    hipLaunchKernelGGL(gemm2_update, g2, blk, 0, stream, X, D, A);
    for (int it = 1; it < NIT; ++it) {
        hipLaunchKernelGGL(gemm1_resid, g1, blk, 0, stream, A, D, X, R);
        hipLaunchKernelGGL(gemm2_update, g2, blk, 0, stream, R, D, A);
    }
    hipLaunchKernelGGL(topk_kernel, dim3(BATCH), blk, 0, stream, A);
}